// Round 8
// baseline (232.814 us; speedup 1.0000x reference)
//
#include <hip/hip_runtime.h>
#include <math.h>

#define BBATCH 64
#define LL 200
#define DD 300
#define PP 16
#define EPSV 1e-12f
#define KG 320          // global K-pad (10 chunks of 32)
#define PS 328          // maxsim LDS row stride in halfs (656 B: 4-bank row shift)
#define NCH 10
#define SRS 308         // prep LDS row stride in f32: 308 mod 32 = 12 -> 8-row groups hit all 32 banks

typedef _Float16 f16x8 __attribute__((ext_vector_type(8)));
typedef float f32x4v __attribute__((ext_vector_type(4)));

// ---------------- prep: norms + f16 conversion + ksq frag table --------------------------
// grid (7, 2, 64), block 256. 32 rows/block. which=0: h1 + n1inv(f32); which=1: h2 + n2inv(f16).
// (which==1, grp==6, b==0) also emits ksqt = f16(kp^2) in 16x16x32 A/B-frag layout.
__global__ __launch_bounds__(256) void prep_kernel(const float* __restrict__ s1,
                                                   const float* __restrict__ s2,
                                                   const float* __restrict__ kern,
                                                   float* __restrict__ n1inv,
                                                   _Float16* __restrict__ n2inv,
                                                   _Float16* __restrict__ h1,
                                                   _Float16* __restrict__ h2,
                                                   _Float16* __restrict__ ksqt) {
    const int grp   = blockIdx.x;   // 0..6 (32-row groups)
    const int which = blockIdx.y;
    const int b     = blockIdx.z;
    const float* s  = which ? s2 : s1;
    _Float16* hout  = which ? h2 : h1;
    const int r0    = grp * 32;
    const int t     = threadIdx.x;

    __shared__ float sr[32][SRS];    // 38.5 KB
    __shared__ float kq2[16][SRS];   // 19.25 KB  (total 57.75 KB -> 2 blocks/CU)

    // stage k^2 (squared once here)
    for (int idx = t; idx < 16 * 75; idx += 256) {
        int p = idx / 75, c4 = (idx - p * 75) * 4;
        float4 kv = *(const float4*)&kern[p * DD + c4];
        kv.x *= kv.x; kv.y *= kv.y; kv.z *= kv.z; kv.w *= kv.w;
        *(float4*)&kq2[p][c4] = kv;
    }
    // stage s rows (coalesced float4)
    for (int idx = t; idx < 32 * 75; idx += 256) {
        int r = idx / 75, c4 = (idx - r * 75) * 4;
        int row = r0 + r;
        float4 v = make_float4(0.f, 0.f, 0.f, 0.f);
        if (row < LL) v = *(const float4*)&s[((size_t)b * LL + row) * DD + c4];
        *(float4*)&sr[r][c4] = v;
    }
    // zero tails [300..307] so 8-wide f16 emit / frag gen can read freely
    {
        int r = t >> 3, cc = 300 + (t & 7);
        sr[r][cc] = 0.f;
        if (r < 16) kq2[r][cc] = 0.f;
    }
    __syncthreads();

    // norms: thread (r = t>>3, pq = t&7) computes p = pq and pq+8; conflict-free banks.
    {
        const int r = t >> 3, pq = t & 7;
        float acc0 = 0.f, acc1 = 0.f;
        for (int c4 = 0; c4 < 75; c4++) {
            float4 a  = *(const float4*)&sr[r][c4 * 4];
            float4 k0 = *(const float4*)&kq2[pq][c4 * 4];
            float4 k1 = *(const float4*)&kq2[pq + 8][c4 * 4];
            float x0 = a.x * a.x, x1 = a.y * a.y, x2 = a.z * a.z, x3 = a.w * a.w;
            acc0 += x0 * k0.x + x1 * k0.y + x2 * k0.z + x3 * k0.w;
            acc1 += x0 * k1.x + x1 * k1.y + x2 * k1.z + x3 * k1.w;
        }
        int row = r0 + r;
        if (row < LL) {
            float i0 = 1.0f / sqrtf(fmaxf(acc0, EPSV));
            float i1 = 1.0f / sqrtf(fmaxf(acc1, EPSV));
            if (which) {
                n2inv[((size_t)b * LL + row) * PP + pq]     = (_Float16)i0;
                n2inv[((size_t)b * LL + row) * PP + pq + 8] = (_Float16)i1;
            } else {
                n1inv[((size_t)b * LL + row) * PP + pq]     = i0;
                n1inv[((size_t)b * LL + row) * PP + pq + 8] = i1;
            }
        }
    }

    // emit f16 rows (row-major, K-padded to 320)
    for (int idx = t; idx < 32 * 40; idx += 256) {
        int r = idx / 40, e0 = (idx - r * 40) * 8;
        int row = r0 + r;
        if (row >= LL) continue;
        f16x8 h;
        if (e0 < 304) {
            float4 a = *(const float4*)&sr[r][e0];
            float4 d = *(const float4*)&sr[r][e0 + 4];
            h[0] = (_Float16)a.x; h[1] = (_Float16)a.y; h[2] = (_Float16)a.z; h[3] = (_Float16)a.w;
            h[4] = (_Float16)d.x; h[5] = (_Float16)d.y; h[6] = (_Float16)d.z; h[7] = (_Float16)d.w;
        } else {
#pragma unroll
            for (int e = 0; e < 8; e++) h[e] = (_Float16)0.f;
        }
        *(f16x8*)&hout[((size_t)b * LL + row) * KG + e0] = h;
    }

    // ksq frag table: ksqt[((ch*4+quad)*16+p)*8 + e] = f16(kp[p][ch*32+quad*8+e]^2)
    if (which == 1 && grp == 6 && b == 0) {
        for (int ent = t; ent < 640; ent += 256) {
            int ch = ent / 64, rem = ent - ch * 64;
            int quad = rem >> 4, p = rem & 15;
            int k0 = ch * 32 + quad * 8;
            f16x8 h;
            if (k0 < 304) {
                float4 a = *(const float4*)&kq2[p][k0];
                float4 d = *(const float4*)&kq2[p][k0 + 4];
                h[0] = (_Float16)(a.x); h[1] = (_Float16)(a.y);
                h[2] = (_Float16)(a.z); h[3] = (_Float16)(a.w);
                h[4] = (_Float16)(d.x); h[5] = (_Float16)(d.y);
                h[6] = (_Float16)(d.z); h[7] = (_Float16)(d.w);
            } else {
#pragma unroll
                for (int e = 0; e < 8; e++) h[e] = (_Float16)0.f;
            }
            *(f16x8*)&ksqt[(size_t)ent * 8] = h;
        }
    }
}

// ---------------- maxsim: 512-thr / 8-wave blocks, A+B tiles in LDS ----------------------
// Allocator model (r4/r6/r7 decoded): waves_per_eu=2 (explicit OR implied by a 512-thr
// block) sets unified budget 256/wave, split FIXED 128 arch + 128 acc. So 2 waves/SIMD
// requires ARCH <= 128 (acc up to 128 AGPR is fine). The persistent af[2][10] (80 regs)
// is what blew arch to ~190 in r4/r7 -> back to LDS-resident A (r0 dataflow), af loaded
// per-ch (8 live regs). Arch demand now ~95-110 <= 128: first spill-free 2-waves/SIMD build.
// grid 256 = (b) x (iblk) x (jblk) -> exactly 1 block/CU. 8 waves = 4 i-subtiles (wi,
// 32 rows each) x 2 p-groups (wp: p in [wp*8, wp*8+8)). LDS 161 KB: A 128xPS + B 112xPS + n2.
// iblk0 rows 0-127, iblk1 rows 72-199 (overlap writes bit-identical, benign).
// acc[2][2][4] = 128 AGPR exactly; j-tiles split {4,3}. Each hb ds_read feeds 4 MFMAs;
// per-block: MFMA ~43.5k cyc vs LDS ~42k cyc, overlapped across 2 waves/SIMD.
__global__ __launch_bounds__(512, 1) void maxsim_kernel(const _Float16* __restrict__ h1,
                                                        const _Float16* __restrict__ h2,
                                                        const _Float16* __restrict__ ksqt,
                                                        const _Float16* __restrict__ n2inv,
                                                        float* __restrict__ part) {
    extern __shared__ __align__(16) char smem[];
    _Float16* h1s = (_Float16*)smem;          // 128*PS halfs = 83,968 B
    _Float16* h2s = h1s + 128 * PS;           // 112*PS halfs = 73,472 B
    _Float16* n2s = h2s + 112 * PS;           // 112*16 halfs =  3,584 B (total 161,024)

    const int blk  = blockIdx.x;              // 256 = b(64) x iblk(2) x jblk(2)
    const int b    = blk & 63;
    const int v    = blk >> 6;                // 0..3
    const int iblk = v & 1;
    const int jblk = v >> 1;
    const int i0   = iblk ? 72 : 0;
    const int j0   = jblk ? 88 : 0;
    const int t    = threadIdx.x;

    // stage A tile (128 rows), B tile (112 rows), n2 (row-contiguous -> padded LDS)
    {
        const _Float16* g1 = h1 + ((size_t)b * LL + i0) * KG;
        for (int idx = t; idx < 128 * 40; idx += 512) {
            int r = idx / 40, q = idx - r * 40;
            *(f16x8*)&h1s[r * PS + q * 8] = *(const f16x8*)&g1[(size_t)idx * 8];
        }
        const _Float16* g2 = h2 + ((size_t)b * LL + j0) * KG;
        for (int idx = t; idx < 112 * 40; idx += 512) {
            int r = idx / 40, q = idx - r * 40;
            *(f16x8*)&h2s[r * PS + q * 8] = *(const f16x8*)&g2[(size_t)idx * 8];
        }
        const _Float16* gn = n2inv + ((size_t)b * LL + j0) * PP;
        for (int idx = t; idx < 224; idx += 512)
            *(f16x8*)&n2s[idx * 8] = *(const f16x8*)&gn[(size_t)idx * 8];
    }
    __syncthreads();

    const int lane = t & 63;
    const int w    = t >> 6;                  // 8 waves
    const int wi   = w & 3;                   // i-subtile: rows [wi*32, wi*32+32) of tile
    const int wp   = w >> 2;                  // p-group: p in [wp*8, wp*8+8)
    const int c    = lane & 15;
    const int quad = lane >> 4;
    const int ibase = wi * 32;                // LDS-tile-relative

    for (int pp = 0; pp < 4; pp++) {
        const int p0 = wp * 8 + pp * 2;
        float rmax[2][2][4];                   // [pq][it][r], 16 VGPR, persists across passes
#pragma unroll
        for (int pq = 0; pq < 2; pq++)
#pragma unroll
            for (int it = 0; it < 2; it++)
#pragma unroll
                for (int r = 0; r < 4; r++) rmax[pq][it][r] = -INFINITY;

#pragma unroll
        for (int pass = 0; pass < 2; pass++) {
            const int jt0 = pass * 4;
            const int jn  = pass ? 3 : 4;      // 7 j-tiles split {4,3}
            f32x4v acc[2][2][4];               // [pq][it][jt] = 128 AGPR (the full acc file)
#pragma unroll
            for (int pq = 0; pq < 2; pq++)
#pragma unroll
                for (int it = 0; it < 2; it++)
#pragma unroll
                    for (int jt = 0; jt < 4; jt++) acc[pq][it][jt] = (f32x4v)0.f;

            // kq rotating buffer, prefetch distance 2 (L2-hot 10 KB table)
            f16x8 kq[2][2];
            kq[0][0] = *(const f16x8*)&ksqt[quad * 128 + p0 * 8];
            kq[0][1] = *(const f16x8*)&ksqt[quad * 128 + p0 * 8 + 8];
            kq[1][0] = *(const f16x8*)&ksqt[512 + quad * 128 + p0 * 8];
            kq[1][1] = *(const f16x8*)&ksqt[512 + quad * 128 + p0 * 8 + 8];
#pragma unroll
            for (int ch = 0; ch < NCH; ch++) {
                const int cur = ch & 1;
                // A fragments from LDS (8 live regs, not 80 persistent)
                f16x8 af0 = *(const f16x8*)&h1s[(ibase + c) * PS + ch * 32 + quad * 8];
                f16x8 af1 = *(const f16x8*)&h1s[(ibase + 16 + c) * PS + ch * 32 + quad * 8];
                // fold ksq into the A side: 4 pk_muls feed up to 16 MFMAs
                f16x8 sa00 = af0 * kq[cur][0];
                f16x8 sa10 = af1 * kq[cur][0];
                f16x8 sa01 = af0 * kq[cur][1];
                f16x8 sa11 = af1 * kq[cur][1];
                if (ch < NCH - 2) {            // refill consumed slot for ch+2
                    kq[cur][0] = *(const f16x8*)&ksqt[(ch + 2) * 512 + quad * 128 + p0 * 8];
                    kq[cur][1] = *(const f16x8*)&ksqt[(ch + 2) * 512 + quad * 128 + p0 * 8 + 8];
                }
#pragma unroll
                for (int jt = 0; jt < 4; jt++) {
                    if (jt < jn) {
                        f16x8 hb = *(const f16x8*)&h2s[((jt0 + jt) * 16 + c) * PS + ch * 32 + quad * 8];
                        acc[0][0][jt] = __builtin_amdgcn_mfma_f32_16x16x32_f16(sa00, hb, acc[0][0][jt], 0, 0, 0);
                        acc[0][1][jt] = __builtin_amdgcn_mfma_f32_16x16x32_f16(sa10, hb, acc[0][1][jt], 0, 0, 0);
                        acc[1][0][jt] = __builtin_amdgcn_mfma_f32_16x16x32_f16(sa01, hb, acc[1][0][jt], 0, 0, 0);
                        acc[1][1][jt] = __builtin_amdgcn_mfma_f32_16x16x32_f16(sa11, hb, acc[1][1][jt], 0, 0, 0);
                    }
                }
            }
            // fold this pass into rmax: scale cols by n2, max over j-tiles
#pragma unroll
            for (int pq = 0; pq < 2; pq++)
#pragma unroll
                for (int jt = 0; jt < 4; jt++) {
                    if (jt < jn) {
                        float n2 = (float)n2s[((jt0 + jt) * 16 + c) * PP + p0 + pq];
#pragma unroll
                        for (int it = 0; it < 2; it++)
#pragma unroll
                            for (int r = 0; r < 4; r++)
                                rmax[pq][it][r] = fmaxf(rmax[pq][it][r], acc[pq][it][jt][r] * n2);
                    }
                }
        }

        // reduce over j-col (lane bits 0..3) and write (C/D: col=lane&15=j, row=quad*4+r)
#pragma unroll
        for (int pq = 0; pq < 2; pq++) {
#pragma unroll
            for (int m = 1; m <= 8; m <<= 1)
#pragma unroll
                for (int it = 0; it < 2; it++)
#pragma unroll
                    for (int r = 0; r < 4; r++)
                        rmax[pq][it][r] = fmaxf(rmax[pq][it][r], __shfl_xor(rmax[pq][it][r], m));
            if (c == 0) {
#pragma unroll
                for (int it = 0; it < 2; it++)
#pragma unroll
                    for (int r = 0; r < 4; r++) {
                        int i = i0 + ibase + it * 16 + quad * 4 + r;   // < 200 by construction
                        part[((size_t)jblk * BBATCH + b) * (LL * PP) + (size_t)i * PP + p0 + pq] = rmax[pq][it][r];
                    }
            }
        }
    }
}

// ---------------- reduce: out = max(part0, part1) * n1inv --------------------------------
__global__ __launch_bounds__(256) void reduce_kernel(const float* __restrict__ part,
                                                     const float* __restrict__ n1inv,
                                                     float* __restrict__ out) {
    int tid = blockIdx.x * 256 + threadIdx.x;
    if (tid >= BBATCH * LL * PP) return;
    out[tid] = fmaxf(part[tid], part[(size_t)BBATCH * LL * PP + tid]) * n1inv[tid];
}

extern "C" void kernel_launch(void* const* d_in, const int* in_sizes, int n_in,
                              void* d_out, int out_size, void* d_ws, size_t ws_size,
                              hipStream_t stream) {
    const float* sent1  = (const float*)d_in[0];   // (64,200,300) f32
    const float* sent2  = (const float*)d_in[1];   // (64,200,300) f32
    const float* kernel = (const float*)d_in[2];   // (16,300)     f32
    float* out = (float*)d_out;                    // (64,200,16)  f32

    char* ws = (char*)d_ws;
    float*    n1inv = (float*)ws;                  ws += (size_t)BBATCH * LL * PP * 4;   // 0.82 MB
    _Float16* n2inv = (_Float16*)ws;               ws += (size_t)BBATCH * LL * PP * 2;   // 0.41 MB
    _Float16* h1    = (_Float16*)ws;               ws += (size_t)BBATCH * LL * KG * 2;   // 8.19 MB
    _Float16* h2    = (_Float16*)ws;               ws += (size_t)BBATCH * LL * KG * 2;   // 8.19 MB
    _Float16* ksqt  = (_Float16*)ws;               ws += (size_t)640 * 8 * 2;            // 10 KB
    float*    part  = (float*)ws;                  // 2*64*200*16 f32 = 1.64 MB (total ~19.3 MB)

    prep_kernel<<<dim3(7, 2, BBATCH), 256, 0, stream>>>(sent1, sent2, kernel,
                                                        n1inv, n2inv, h1, h2, ksqt);

    const int lds_bytes = (128 * PS + 112 * PS + 112 * PP) * 2;   // 161,024 B -> 1 block/CU
    hipFuncSetAttribute((const void*)maxsim_kernel,
                        hipFuncAttributeMaxDynamicSharedMemorySize, lds_bytes);
    maxsim_kernel<<<dim3(256, 1, 1), 512, lds_bytes, stream>>>(h1, h2, ksqt, n2inv, part);

    int nout = BBATCH * LL * PP;
    reduce_kernel<<<(nout + 255) / 256, 256, 0, stream>>>(part, n1inv, out);
}

// Round 9
// 167.317 us; speedup vs baseline: 1.3915x; 1.3915x over previous
//
#include <hip/hip_runtime.h>
#include <math.h>

#define BBATCH 64
#define LL 200
#define DD 300
#define PP 16
#define EPSV 1e-12f
#define KG 320          // global K-pad (10 chunks of 32)
#define PS 328          // maxsim LDS row stride in halfs (656 B: 4-bank row shift)
#define NCH 10
#define SRS 308         // prep LDS row stride in f32: 308 mod 32 = 12 -> 8-row groups hit all 32 banks

typedef _Float16 f16x8 __attribute__((ext_vector_type(8)));
typedef float f32x4v __attribute__((ext_vector_type(4)));

// ---------------- prep: norms + f16 conversion + ksq frag table --------------------------
// grid (7, 2, 64), block 256. 32 rows/block. which=0: h1 + n1inv(f32); which=1: h2 + n2inv(f16).
// (which==1, grp==6, b==0) also emits ksqt = f16(kp^2) in 16x16x32 A/B-frag layout.
__global__ __launch_bounds__(256) void prep_kernel(const float* __restrict__ s1,
                                                   const float* __restrict__ s2,
                                                   const float* __restrict__ kern,
                                                   float* __restrict__ n1inv,
                                                   _Float16* __restrict__ n2inv,
                                                   _Float16* __restrict__ h1,
                                                   _Float16* __restrict__ h2,
                                                   _Float16* __restrict__ ksqt) {
    const int grp   = blockIdx.x;   // 0..6 (32-row groups)
    const int which = blockIdx.y;
    const int b     = blockIdx.z;
    const float* s  = which ? s2 : s1;
    _Float16* hout  = which ? h2 : h1;
    const int r0    = grp * 32;
    const int t     = threadIdx.x;

    __shared__ float sr[32][SRS];    // 38.5 KB
    __shared__ float kq2[16][SRS];   // 19.25 KB  (total 57.75 KB -> 2 blocks/CU)

    // stage k^2 (squared once here)
    for (int idx = t; idx < 16 * 75; idx += 256) {
        int p = idx / 75, c4 = (idx - p * 75) * 4;
        float4 kv = *(const float4*)&kern[p * DD + c4];
        kv.x *= kv.x; kv.y *= kv.y; kv.z *= kv.z; kv.w *= kv.w;
        *(float4*)&kq2[p][c4] = kv;
    }
    // stage s rows (coalesced float4)
    for (int idx = t; idx < 32 * 75; idx += 256) {
        int r = idx / 75, c4 = (idx - r * 75) * 4;
        int row = r0 + r;
        float4 v = make_float4(0.f, 0.f, 0.f, 0.f);
        if (row < LL) v = *(const float4*)&s[((size_t)b * LL + row) * DD + c4];
        *(float4*)&sr[r][c4] = v;
    }
    // zero tails [300..307] so 8-wide f16 emit / frag gen can read freely
    {
        int r = t >> 3, cc = 300 + (t & 7);
        sr[r][cc] = 0.f;
        if (r < 16) kq2[r][cc] = 0.f;
    }
    __syncthreads();

    // norms: thread (r = t>>3, pq = t&7) computes p = pq and pq+8; conflict-free banks.
    {
        const int r = t >> 3, pq = t & 7;
        float acc0 = 0.f, acc1 = 0.f;
        for (int c4 = 0; c4 < 75; c4++) {
            float4 a  = *(const float4*)&sr[r][c4 * 4];
            float4 k0 = *(const float4*)&kq2[pq][c4 * 4];
            float4 k1 = *(const float4*)&kq2[pq + 8][c4 * 4];
            float x0 = a.x * a.x, x1 = a.y * a.y, x2 = a.z * a.z, x3 = a.w * a.w;
            acc0 += x0 * k0.x + x1 * k0.y + x2 * k0.z + x3 * k0.w;
            acc1 += x0 * k1.x + x1 * k1.y + x2 * k1.z + x3 * k1.w;
        }
        int row = r0 + r;
        if (row < LL) {
            float i0 = 1.0f / sqrtf(fmaxf(acc0, EPSV));
            float i1 = 1.0f / sqrtf(fmaxf(acc1, EPSV));
            if (which) {
                n2inv[((size_t)b * LL + row) * PP + pq]     = (_Float16)i0;
                n2inv[((size_t)b * LL + row) * PP + pq + 8] = (_Float16)i1;
            } else {
                n1inv[((size_t)b * LL + row) * PP + pq]     = i0;
                n1inv[((size_t)b * LL + row) * PP + pq + 8] = i1;
            }
        }
    }

    // emit f16 rows (row-major, K-padded to 320)
    for (int idx = t; idx < 32 * 40; idx += 256) {
        int r = idx / 40, e0 = (idx - r * 40) * 8;
        int row = r0 + r;
        if (row >= LL) continue;
        f16x8 h;
        if (e0 < 304) {
            float4 a = *(const float4*)&sr[r][e0];
            float4 d = *(const float4*)&sr[r][e0 + 4];
            h[0] = (_Float16)a.x; h[1] = (_Float16)a.y; h[2] = (_Float16)a.z; h[3] = (_Float16)a.w;
            h[4] = (_Float16)d.x; h[5] = (_Float16)d.y; h[6] = (_Float16)d.z; h[7] = (_Float16)d.w;
        } else {
#pragma unroll
            for (int e = 0; e < 8; e++) h[e] = (_Float16)0.f;
        }
        *(f16x8*)&hout[((size_t)b * LL + row) * KG + e0] = h;
    }

    // ksq frag table: ksqt[((ch*4+quad)*16+p)*8 + e] = f16(kp[p][ch*32+quad*8+e]^2)
    if (which == 1 && grp == 6 && b == 0) {
        for (int ent = t; ent < 640; ent += 256) {
            int ch = ent / 64, rem = ent - ch * 64;
            int quad = rem >> 4, p = rem & 15;
            int k0 = ch * 32 + quad * 8;
            f16x8 h;
            if (k0 < 304) {
                float4 a = *(const float4*)&kq2[p][k0];
                float4 d = *(const float4*)&kq2[p][k0 + 4];
                h[0] = (_Float16)(a.x); h[1] = (_Float16)(a.y);
                h[2] = (_Float16)(a.z); h[3] = (_Float16)(a.w);
                h[4] = (_Float16)(d.x); h[5] = (_Float16)(d.y);
                h[6] = (_Float16)(d.z); h[7] = (_Float16)(d.w);
            } else {
#pragma unroll
                for (int e = 0; e < 8; e++) h[e] = (_Float16)0.f;
            }
            *(f16x8*)&ksqt[(size_t)ent * 8] = h;
        }
    }
}

// ---------------- maxsim: r6 base + ksq-in-LDS + explicit distance-1 LDS pipeline --------
// Allocator model (r4-r8, final): any multi-wave launch_bounds request caps ARCH VGPRs at
// 128 (spills, ~500 MB scratch); (256,1) is the only spill-free regime (r6: 256 arch +
// 64 acc = 320 unified -> 6 waves/CU -> 1 block/CU, Occ ~10%). Occupancy is structurally
// capped -> attack EXPOSED LATENCY within the single wave instead:
//  (a) ksqt copied to LDS (10 KB; total 87 KB): removes all inner-loop GLOBAL loads
//      (were ~200-cyc L2 hits with vmcnt waits right before the sa-muls).
//  (b) explicit cur/next rotation for kq+hb: ch+1's 4 ds_reads issue at top of iter ch,
//      consumed top of ch+1 -> ~119 cyc of intervening issue covers the ~120-cyc LDS
//      latency. +~24 arch regs (total ~240, still spill-free at (256,1)).
// grid 512 = (b) x (iblk) x (pgrp) x (jblk); 4 waves; af[2][10] persistent (80 VGPR,
// loaded once from L2-hot h1). j-tiles split {2,2,2,1} -> acc[2][2][2] = 64 acc regs.
// iblk0 rows 0-127, iblk1 rows 72-199 (overlap writes bit-identical, benign).
__global__ __launch_bounds__(256, 1) void maxsim_kernel(const _Float16* __restrict__ h1,
                                                        const _Float16* __restrict__ h2,
                                                        const _Float16* __restrict__ ksqt,
                                                        const _Float16* __restrict__ n2inv,
                                                        float* __restrict__ part) {
    extern __shared__ __align__(16) char smem[];
    _Float16* h2s = (_Float16*)smem;          // 112*PS halfs = 73,472 B
    _Float16* n2s = h2s + 112 * PS;           // 112*16 halfs =  3,584 B
    _Float16* kqs = n2s + 112 * PP;           // 5120 halfs   = 10,240 B (total 87,296)

    const int blk  = blockIdx.x;
    const int b    = blk & 63;
    const int v    = blk >> 6;                // 0..7
    const int iblk = v & 1;
    const int pgrp = (v >> 1) & 1;
    const int jblk = v >> 2;
    const int i0   = iblk ? 72 : 0;
    const int j0   = jblk ? 88 : 0;
    const int t    = threadIdx.x;

    const int lane = t & 63;
    const int w    = t >> 6;                  // 4 waves
    const int c    = lane & 15;
    const int quad = lane >> 4;
    const int ibase = i0 + w * 32;

    // A fragments: global -> registers (20 x b128 = 80 VGPR; h1 is L2/L3-hot)
    f16x8 af[2][NCH];
    {
        const _Float16* g1 = h1 + (size_t)b * LL * KG;
#pragma unroll
        for (int it = 0; it < 2; it++)
#pragma unroll
            for (int ch = 0; ch < NCH; ch++)
                af[it][ch] = *(const f16x8*)&g1[(size_t)(ibase + it * 16 + c) * KG + ch * 32 + quad * 8];
    }

    // stage B tile (112 rows) + n2 + ksq table (10 KB) into LDS
    {
        const _Float16* g2 = h2 + ((size_t)b * LL + j0) * KG;
        for (int idx = t; idx < 112 * 40; idx += 256) {
            int r = idx / 40, q = idx - r * 40;
            *(f16x8*)&h2s[r * PS + q * 8] = *(const f16x8*)&g2[(size_t)idx * 8];
        }
        const _Float16* gn = n2inv + ((size_t)b * LL + j0) * PP;
        for (int idx = t; idx < 224; idx += 256)
            *(f16x8*)&n2s[idx * 8] = *(const f16x8*)&gn[(size_t)idx * 8];
        for (int idx = t; idx < 640; idx += 256)
            *(f16x8*)&kqs[idx * 8] = *(const f16x8*)&ksqt[(size_t)idx * 8];
    }
    __syncthreads();

    for (int pp = 0; pp < 4; pp++) {
        const int p0 = pgrp * 8 + pp * 2;
        float rmax[2][2][4];                   // [pq][it][r], persists across passes
#pragma unroll
        for (int pq = 0; pq < 2; pq++)
#pragma unroll
            for (int it = 0; it < 2; it++)
#pragma unroll
                for (int r = 0; r < 4; r++) rmax[pq][it][r] = -INFINITY;

#pragma unroll
        for (int pass = 0; pass < 4; pass++) {
            const int jt0 = pass * 2;
            const int jn  = (pass < 3) ? 2 : 1;   // 7 j-tiles split {2,2,2,1}
            f32x4v acc[2][2][2];                  // [pq][it][jt] = 64 acc regs
#pragma unroll
            for (int pq = 0; pq < 2; pq++)
#pragma unroll
                for (int it = 0; it < 2; it++)
#pragma unroll
                    for (int jt = 0; jt < 2; jt++) acc[pq][it][jt] = (f32x4v)0.f;

            // prime ch=0 (current regs); all inner-loop loads are now LDS
            f16x8 kq0 = *(const f16x8*)&kqs[quad * 128 + p0 * 8];
            f16x8 kq1 = *(const f16x8*)&kqs[quad * 128 + p0 * 8 + 8];
            f16x8 hb0 = *(const f16x8*)&h2s[(jt0 * 16 + c) * PS + quad * 8];
            f16x8 hb1 = hb0;
            if (jn > 1) hb1 = *(const f16x8*)&h2s[((jt0 + 1) * 16 + c) * PS + quad * 8];

#pragma unroll
            for (int ch = 0; ch < NCH; ch++) {
                // issue ch+1 loads FIRST: consumed at top of next iter (~119 cyc later)
                f16x8 kq0n = kq0, kq1n = kq1, hb0n = hb0, hb1n = hb1;
                if (ch < NCH - 1) {
                    kq0n = *(const f16x8*)&kqs[(ch + 1) * 512 + quad * 128 + p0 * 8];
                    kq1n = *(const f16x8*)&kqs[(ch + 1) * 512 + quad * 128 + p0 * 8 + 8];
                    hb0n = *(const f16x8*)&h2s[(jt0 * 16 + c) * PS + (ch + 1) * 32 + quad * 8];
                    if (jn > 1)
                        hb1n = *(const f16x8*)&h2s[((jt0 + 1) * 16 + c) * PS + (ch + 1) * 32 + quad * 8];
                }
                // fold ksq into the A side: 4 pk_muls feed up to 8 MFMAs
                f16x8 sa00 = af[0][ch] * kq0;
                f16x8 sa10 = af[1][ch] * kq0;
                f16x8 sa01 = af[0][ch] * kq1;
                f16x8 sa11 = af[1][ch] * kq1;
                acc[0][0][0] = __builtin_amdgcn_mfma_f32_16x16x32_f16(sa00, hb0, acc[0][0][0], 0, 0, 0);
                acc[0][1][0] = __builtin_amdgcn_mfma_f32_16x16x32_f16(sa10, hb0, acc[0][1][0], 0, 0, 0);
                acc[1][0][0] = __builtin_amdgcn_mfma_f32_16x16x32_f16(sa01, hb0, acc[1][0][0], 0, 0, 0);
                acc[1][1][0] = __builtin_amdgcn_mfma_f32_16x16x32_f16(sa11, hb0, acc[1][1][0], 0, 0, 0);
                if (jn > 1) {
                    acc[0][0][1] = __builtin_amdgcn_mfma_f32_16x16x32_f16(sa00, hb1, acc[0][0][1], 0, 0, 0);
                    acc[0][1][1] = __builtin_amdgcn_mfma_f32_16x16x32_f16(sa10, hb1, acc[0][1][1], 0, 0, 0);
                    acc[1][0][1] = __builtin_amdgcn_mfma_f32_16x16x32_f16(sa01, hb1, acc[1][0][1], 0, 0, 0);
                    acc[1][1][1] = __builtin_amdgcn_mfma_f32_16x16x32_f16(sa11, hb1, acc[1][1][1], 0, 0, 0);
                }
                kq0 = kq0n; kq1 = kq1n; hb0 = hb0n; hb1 = hb1n;
            }
            // fold this pass into rmax: scale cols by n2, max over j-tiles
#pragma unroll
            for (int pq = 0; pq < 2; pq++)
#pragma unroll
                for (int jt = 0; jt < 2; jt++) {
                    if (jt < jn) {
                        float n2 = (float)n2s[((jt0 + jt) * 16 + c) * PP + p0 + pq];
#pragma unroll
                        for (int it = 0; it < 2; it++)
#pragma unroll
                            for (int r = 0; r < 4; r++)
                                rmax[pq][it][r] = fmaxf(rmax[pq][it][r], acc[pq][it][jt][r] * n2);
                    }
                }
        }

        // reduce over j-col (lane bits 0..3) and write (C/D: col=lane&15=j, row=quad*4+r)
#pragma unroll
        for (int pq = 0; pq < 2; pq++) {
#pragma unroll
            for (int m = 1; m <= 8; m <<= 1)
#pragma unroll
                for (int it = 0; it < 2; it++)
#pragma unroll
                    for (int r = 0; r < 4; r++)
                        rmax[pq][it][r] = fmaxf(rmax[pq][it][r], __shfl_xor(rmax[pq][it][r], m));
            if (c == 0) {
#pragma unroll
                for (int it = 0; it < 2; it++)
#pragma unroll
                    for (int r = 0; r < 4; r++) {
                        int i = ibase + it * 16 + quad * 4 + r;   // < 200 by construction
                        part[((size_t)jblk * BBATCH + b) * (LL * PP) + (size_t)i * PP + p0 + pq] = rmax[pq][it][r];
                    }
            }
        }
    }
}

// ---------------- reduce: out = max(part0, part1) * n1inv --------------------------------
__global__ __launch_bounds__(256) void reduce_kernel(const float* __restrict__ part,
                                                     const float* __restrict__ n1inv,
                                                     float* __restrict__ out) {
    int tid = blockIdx.x * 256 + threadIdx.x;
    if (tid >= BBATCH * LL * PP) return;
    out[tid] = fmaxf(part[tid], part[(size_t)BBATCH * LL * PP + tid]) * n1inv[tid];
}

extern "C" void kernel_launch(void* const* d_in, const int* in_sizes, int n_in,
                              void* d_out, int out_size, void* d_ws, size_t ws_size,
                              hipStream_t stream) {
    const float* sent1  = (const float*)d_in[0];   // (64,200,300) f32
    const float* sent2  = (const float*)d_in[1];   // (64,200,300) f32
    const float* kernel = (const float*)d_in[2];   // (16,300)     f32
    float* out = (float*)d_out;                    // (64,200,16)  f32

    char* ws = (char*)d_ws;
    float*    n1inv = (float*)ws;                  ws += (size_t)BBATCH * LL * PP * 4;   // 0.82 MB
    _Float16* n2inv = (_Float16*)ws;               ws += (size_t)BBATCH * LL * PP * 2;   // 0.41 MB
    _Float16* h1    = (_Float16*)ws;               ws += (size_t)BBATCH * LL * KG * 2;   // 8.19 MB
    _Float16* h2    = (_Float16*)ws;               ws += (size_t)BBATCH * LL * KG * 2;   // 8.19 MB
    _Float16* ksqt  = (_Float16*)ws;               ws += (size_t)640 * 8 * 2;            // 10 KB
    float*    part  = (float*)ws;                  // 2*64*200*16 f32 = 1.64 MB (total ~19.3 MB)

    prep_kernel<<<dim3(7, 2, BBATCH), 256, 0, stream>>>(sent1, sent2, kernel,
                                                        n1inv, n2inv, h1, h2, ksqt);

    const int lds_bytes = (112 * PS + 112 * PP + 5120) * 2;   // 87,296 B
    hipFuncSetAttribute((const void*)maxsim_kernel,
                        hipFuncAttributeMaxDynamicSharedMemorySize, lds_bytes);
    maxsim_kernel<<<dim3(512, 1, 1), 256, lds_bytes, stream>>>(h1, h2, ksqt, n2inv, part);

    int nout = BBATCH * LL * PP;
    reduce_kernel<<<(nout + 255) / 256, 256, 0, stream>>>(part, n1inv, out);
}

// Round 10
// 156.447 us; speedup vs baseline: 1.4881x; 1.0695x over previous
//
#include <hip/hip_runtime.h>
#include <math.h>

#define BBATCH 64
#define LL 200
#define DD 300
#define PP 16
#define EPSV 1e-12f
#define KG 320          // global K-pad (10 chunks of 32)
#define PS 328          // maxsim LDS row stride in halfs (656 B: 4-bank row shift)
#define NCH 10
#define SRS 324         // prep LDS row stride in f32 (zeros 300..323 so frag/emit reads are unguarded)

typedef _Float16 f16x8 __attribute__((ext_vector_type(8)));
typedef float f32x4v __attribute__((ext_vector_type(4)));

// ---------------- prep: MFMA norms + f16 conversion + ksq frag table ---------------------
// grid (7, 2, 64), block 256, 32 rows/block. LDS 51.7 KB -> 3 blocks/CU.
// norm[i][p] = sum_d s2[i][d]*k2[p][d] is MFMA-shaped: A-frag = f16(s^2) (squared in f32,
// rounded once), B-frag = kqf = f16(k^2) in the SAME layout maxsim's ksqt uses
// (B[col=p][k]). Waves 0-1: 10-MFMA norm chains (row groups 0/1). Waves 2-3: f16 row emit.
// Replaces r9's 75-iter f32 VALU loop (~2.5 GFLOP total, ~30 us floor) with 20 MFMAs/block.
// Precision: norm rel err ~1e-3 (f16 products, f32 accum) vs f32-exact before.
__global__ __launch_bounds__(256) void prep_kernel(const float* __restrict__ s1,
                                                   const float* __restrict__ s2,
                                                   const float* __restrict__ kern,
                                                   float* __restrict__ n1inv,
                                                   _Float16* __restrict__ n2inv,
                                                   _Float16* __restrict__ h1,
                                                   _Float16* __restrict__ h2,
                                                   _Float16* __restrict__ ksqt) {
    const int grp   = blockIdx.x;   // 0..6 (32-row groups)
    const int which = blockIdx.y;
    const int b     = blockIdx.z;
    const float* s  = which ? s2 : s1;
    _Float16* hout  = which ? h2 : h1;
    const int r0    = grp * 32;
    const int t     = threadIdx.x;

    __shared__ float    sr[32][SRS];   // 41,472 B
    __shared__ _Float16 kqf[640 * 8];  // 10,240 B: f16(k^2), B-frag layout (= ksqt layout)

    // stage s rows (coalesced float4; rows >= 200 zeroed)
    for (int idx = t; idx < 32 * 75; idx += 256) {
        int r = idx / 75, c4 = (idx - r * 75) * 4;
        int row = r0 + r;
        float4 v = make_float4(0.f, 0.f, 0.f, 0.f);
        if (row < LL) v = *(const float4*)&s[((size_t)b * LL + row) * DD + c4];
        *(float4*)&sr[r][c4] = v;
    }
    // zero tail cols 300..323 (covers frag reads to 319 and emit to 319)
    for (int idx = t; idx < 32 * 24; idx += 256) {
        int r = idx / 24, cc = 300 + (idx - r * 24);
        sr[r][cc] = 0.f;
    }
    // build kqf[ent=(ch*4+quad)*16+p][e] = f16(kern[p][ch*32+quad*8+e]^2)  (kern is L2-hot)
    for (int ent = t; ent < 640; ent += 256) {
        int ch = ent >> 6, rem = ent & 63;
        int quad = rem >> 4, p = rem & 15;
        int k0 = ch * 32 + quad * 8;
        f16x8 h;
        if (k0 + 8 <= DD) {
            float4 a = *(const float4*)&kern[p * DD + k0];
            float4 d = *(const float4*)&kern[p * DD + k0 + 4];
            h[0] = (_Float16)(a.x * a.x); h[1] = (_Float16)(a.y * a.y);
            h[2] = (_Float16)(a.z * a.z); h[3] = (_Float16)(a.w * a.w);
            h[4] = (_Float16)(d.x * d.x); h[5] = (_Float16)(d.y * d.y);
            h[6] = (_Float16)(d.z * d.z); h[7] = (_Float16)(d.w * d.w);
        } else {
#pragma unroll
            for (int e = 0; e < 8; e++) {
                float kv = (k0 + e < DD) ? kern[p * DD + k0 + e] : 0.f;
                h[e] = (_Float16)(kv * kv);
            }
        }
        *(f16x8*)&kqf[ent * 8] = h;
    }
    __syncthreads();

    const int lane = t & 63;
    const int w    = t >> 6;

    if (w < 2) {
        // ---- norms via MFMA: row group rg = w (rows r0+rg*16 .. +15) ----
        const int rg   = w;
        const int c    = lane & 15;
        const int quad = lane >> 4;
        f32x4v nacc = (f32x4v)0.f;
#pragma unroll
        for (int ch = 0; ch < NCH; ch++) {
            float4 a = *(const float4*)&sr[rg * 16 + c][ch * 32 + quad * 8];
            float4 d = *(const float4*)&sr[rg * 16 + c][ch * 32 + quad * 8 + 4];
            f16x8 sa;
            sa[0] = (_Float16)(a.x * a.x); sa[1] = (_Float16)(a.y * a.y);
            sa[2] = (_Float16)(a.z * a.z); sa[3] = (_Float16)(a.w * a.w);
            sa[4] = (_Float16)(d.x * d.x); sa[5] = (_Float16)(d.y * d.y);
            sa[6] = (_Float16)(d.z * d.z); sa[7] = (_Float16)(d.w * d.w);
            f16x8 bk = *(const f16x8*)&kqf[((ch * 4 + quad) * 16 + c) * 8];
            nacc = __builtin_amdgcn_mfma_f32_16x16x32_f16(sa, bk, nacc, 0, 0, 0);
        }
        // C/D: col=lane&15 = p, row = quad*4+r = local i
#pragma unroll
        for (int r = 0; r < 4; r++) {
            int row = r0 + rg * 16 + quad * 4 + r;
            if (row < LL) {
                float inv = 1.0f / sqrtf(fmaxf(nacc[r], EPSV));
                if (which) n2inv[((size_t)b * LL + row) * PP + c] = (_Float16)inv;
                else       n1inv[((size_t)b * LL + row) * PP + c] = inv;
            }
        }
    } else {
        // ---- emit f16 rows (row-major, K-padded to 320; tail comes from zeroed sr) ----
        const int base = (w - 2) * 640;            // waves 2,3 split the 1280 units
        for (int u = base + lane; u < base + 640; u += 64) {
            int r = u / 40, e0 = (u - r * 40) * 8;
            int row = r0 + r;
            if (row < LL) {
                float4 a = *(const float4*)&sr[r][e0];
                float4 d = *(const float4*)&sr[r][e0 + 4];
                f16x8 h;
                h[0] = (_Float16)a.x; h[1] = (_Float16)a.y; h[2] = (_Float16)a.z; h[3] = (_Float16)a.w;
                h[4] = (_Float16)d.x; h[5] = (_Float16)d.y; h[6] = (_Float16)d.z; h[7] = (_Float16)d.w;
                *(f16x8*)&hout[((size_t)b * LL + row) * KG + e0] = h;
            }
        }
    }

    // designated block publishes the global ksqt table (kqf complete since the barrier)
    if (which == 1 && grp == 6 && b == 0) {
        for (int ent = t; ent < 640; ent += 256)
            *(f16x8*)&ksqt[(size_t)ent * 8] = *(const f16x8*)&kqf[ent * 8];
    }
}

// ---------------- maxsim: r6 base + ksq-in-LDS + explicit distance-1 LDS pipeline --------
// (UNCHANGED from r9: 78 us, VGPR 256, spill-free. Allocator model r4-r8: multi-wave
// launch_bounds caps arch VGPRs at 128 -> spill; (256,1) is the only spill-free regime.)
__global__ __launch_bounds__(256, 1) void maxsim_kernel(const _Float16* __restrict__ h1,
                                                        const _Float16* __restrict__ h2,
                                                        const _Float16* __restrict__ ksqt,
                                                        const _Float16* __restrict__ n2inv,
                                                        float* __restrict__ part) {
    extern __shared__ __align__(16) char smem[];
    _Float16* h2s = (_Float16*)smem;          // 112*PS halfs = 73,472 B
    _Float16* n2s = h2s + 112 * PS;           // 112*16 halfs =  3,584 B
    _Float16* kqs = n2s + 112 * PP;           // 5120 halfs   = 10,240 B (total 87,296)

    const int blk  = blockIdx.x;
    const int b    = blk & 63;
    const int v    = blk >> 6;                // 0..7
    const int iblk = v & 1;
    const int pgrp = (v >> 1) & 1;
    const int jblk = v >> 2;
    const int i0   = iblk ? 72 : 0;
    const int j0   = jblk ? 88 : 0;
    const int t    = threadIdx.x;

    const int lane = t & 63;
    const int w    = t >> 6;                  // 4 waves
    const int c    = lane & 15;
    const int quad = lane >> 4;
    const int ibase = i0 + w * 32;

    // A fragments: global -> registers (20 x b128 = 80 VGPR; h1 is L2/L3-hot)
    f16x8 af[2][NCH];
    {
        const _Float16* g1 = h1 + (size_t)b * LL * KG;
#pragma unroll
        for (int it = 0; it < 2; it++)
#pragma unroll
            for (int ch = 0; ch < NCH; ch++)
                af[it][ch] = *(const f16x8*)&g1[(size_t)(ibase + it * 16 + c) * KG + ch * 32 + quad * 8];
    }

    // stage B tile (112 rows) + n2 + ksq table (10 KB) into LDS
    {
        const _Float16* g2 = h2 + ((size_t)b * LL + j0) * KG;
        for (int idx = t; idx < 112 * 40; idx += 256) {
            int r = idx / 40, q = idx - r * 40;
            *(f16x8*)&h2s[r * PS + q * 8] = *(const f16x8*)&g2[(size_t)idx * 8];
        }
        const _Float16* gn = n2inv + ((size_t)b * LL + j0) * PP;
        for (int idx = t; idx < 224; idx += 256)
            *(f16x8*)&n2s[idx * 8] = *(const f16x8*)&gn[(size_t)idx * 8];
        for (int idx = t; idx < 640; idx += 256)
            *(f16x8*)&kqs[idx * 8] = *(const f16x8*)&ksqt[(size_t)idx * 8];
    }
    __syncthreads();

    for (int pp = 0; pp < 4; pp++) {
        const int p0 = pgrp * 8 + pp * 2;
        float rmax[2][2][4];                   // [pq][it][r], persists across passes
#pragma unroll
        for (int pq = 0; pq < 2; pq++)
#pragma unroll
            for (int it = 0; it < 2; it++)
#pragma unroll
                for (int r = 0; r < 4; r++) rmax[pq][it][r] = -INFINITY;

#pragma unroll
        for (int pass = 0; pass < 4; pass++) {
            const int jt0 = pass * 2;
            const int jn  = (pass < 3) ? 2 : 1;   // 7 j-tiles split {2,2,2,1}
            f32x4v acc[2][2][2];                  // [pq][it][jt] = 64 acc regs
#pragma unroll
            for (int pq = 0; pq < 2; pq++)
#pragma unroll
                for (int it = 0; it < 2; it++)
#pragma unroll
                    for (int jt = 0; jt < 2; jt++) acc[pq][it][jt] = (f32x4v)0.f;

            // prime ch=0 (current regs); all inner-loop loads are LDS
            f16x8 kq0 = *(const f16x8*)&kqs[quad * 128 + p0 * 8];
            f16x8 kq1 = *(const f16x8*)&kqs[quad * 128 + p0 * 8 + 8];
            f16x8 hb0 = *(const f16x8*)&h2s[(jt0 * 16 + c) * PS + quad * 8];
            f16x8 hb1 = hb0;
            if (jn > 1) hb1 = *(const f16x8*)&h2s[((jt0 + 1) * 16 + c) * PS + quad * 8];

#pragma unroll
            for (int ch = 0; ch < NCH; ch++) {
                // issue ch+1 loads FIRST: consumed at top of next iter (~119 cyc later)
                f16x8 kq0n = kq0, kq1n = kq1, hb0n = hb0, hb1n = hb1;
                if (ch < NCH - 1) {
                    kq0n = *(const f16x8*)&kqs[(ch + 1) * 512 + quad * 128 + p0 * 8];
                    kq1n = *(const f16x8*)&kqs[(ch + 1) * 512 + quad * 128 + p0 * 8 + 8];
                    hb0n = *(const f16x8*)&h2s[(jt0 * 16 + c) * PS + (ch + 1) * 32 + quad * 8];
                    if (jn > 1)
                        hb1n = *(const f16x8*)&h2s[((jt0 + 1) * 16 + c) * PS + (ch + 1) * 32 + quad * 8];
                }
                // fold ksq into the A side: 4 pk_muls feed up to 8 MFMAs
                f16x8 sa00 = af[0][ch] * kq0;
                f16x8 sa10 = af[1][ch] * kq0;
                f16x8 sa01 = af[0][ch] * kq1;
                f16x8 sa11 = af[1][ch] * kq1;
                acc[0][0][0] = __builtin_amdgcn_mfma_f32_16x16x32_f16(sa00, hb0, acc[0][0][0], 0, 0, 0);
                acc[0][1][0] = __builtin_amdgcn_mfma_f32_16x16x32_f16(sa10, hb0, acc[0][1][0], 0, 0, 0);
                acc[1][0][0] = __builtin_amdgcn_mfma_f32_16x16x32_f16(sa01, hb0, acc[1][0][0], 0, 0, 0);
                acc[1][1][0] = __builtin_amdgcn_mfma_f32_16x16x32_f16(sa11, hb0, acc[1][1][0], 0, 0, 0);
                if (jn > 1) {
                    acc[0][0][1] = __builtin_amdgcn_mfma_f32_16x16x32_f16(sa00, hb1, acc[0][0][1], 0, 0, 0);
                    acc[0][1][1] = __builtin_amdgcn_mfma_f32_16x16x32_f16(sa10, hb1, acc[0][1][1], 0, 0, 0);
                    acc[1][0][1] = __builtin_amdgcn_mfma_f32_16x16x32_f16(sa01, hb1, acc[1][0][1], 0, 0, 0);
                    acc[1][1][1] = __builtin_amdgcn_mfma_f32_16x16x32_f16(sa11, hb1, acc[1][1][1], 0, 0, 0);
                }
                kq0 = kq0n; kq1 = kq1n; hb0 = hb0n; hb1 = hb1n;
            }
            // fold this pass into rmax: scale cols by n2, max over j-tiles
#pragma unroll
            for (int pq = 0; pq < 2; pq++)
#pragma unroll
                for (int jt = 0; jt < 2; jt++) {
                    if (jt < jn) {
                        float n2 = (float)n2s[((jt0 + jt) * 16 + c) * PP + p0 + pq];
#pragma unroll
                        for (int it = 0; it < 2; it++)
#pragma unroll
                            for (int r = 0; r < 4; r++)
                                rmax[pq][it][r] = fmaxf(rmax[pq][it][r], acc[pq][it][jt][r] * n2);
                    }
                }
        }

        // reduce over j-col (lane bits 0..3) and write (C/D: col=lane&15=j, row=quad*4+r)
#pragma unroll
        for (int pq = 0; pq < 2; pq++) {
#pragma unroll
            for (int m = 1; m <= 8; m <<= 1)
#pragma unroll
                for (int it = 0; it < 2; it++)
#pragma unroll
                    for (int r = 0; r < 4; r++)
                        rmax[pq][it][r] = fmaxf(rmax[pq][it][r], __shfl_xor(rmax[pq][it][r], m));
            if (c == 0) {
#pragma unroll
                for (int it = 0; it < 2; it++)
#pragma unroll
                    for (int r = 0; r < 4; r++) {
                        int i = ibase + it * 16 + quad * 4 + r;   // < 200 by construction
                        part[((size_t)jblk * BBATCH + b) * (LL * PP) + (size_t)i * PP + p0 + pq] = rmax[pq][it][r];
                    }
            }
        }
    }
}

// ---------------- reduce: out = max(part0, part1) * n1inv --------------------------------
__global__ __launch_bounds__(256) void reduce_kernel(const float* __restrict__ part,
                                                     const float* __restrict__ n1inv,
                                                     float* __restrict__ out) {
    int tid = blockIdx.x * 256 + threadIdx.x;
    if (tid >= BBATCH * LL * PP) return;
    out[tid] = fmaxf(part[tid], part[(size_t)BBATCH * LL * PP + tid]) * n1inv[tid];
}

extern "C" void kernel_launch(void* const* d_in, const int* in_sizes, int n_in,
                              void* d_out, int out_size, void* d_ws, size_t ws_size,
                              hipStream_t stream) {
    const float* sent1  = (const float*)d_in[0];   // (64,200,300) f32
    const float* sent2  = (const float*)d_in[1];   // (64,200,300) f32
    const float* kernel = (const float*)d_in[2];   // (16,300)     f32
    float* out = (float*)d_out;                    // (64,200,16)  f32

    char* ws = (char*)d_ws;
    float*    n1inv = (float*)ws;                  ws += (size_t)BBATCH * LL * PP * 4;   // 0.82 MB
    _Float16* n2inv = (_Float16*)ws;               ws += (size_t)BBATCH * LL * PP * 2;   // 0.41 MB
    _Float16* h1    = (_Float16*)ws;               ws += (size_t)BBATCH * LL * KG * 2;   // 8.19 MB
    _Float16* h2    = (_Float16*)ws;               ws += (size_t)BBATCH * LL * KG * 2;   // 8.19 MB
    _Float16* ksqt  = (_Float16*)ws;               ws += (size_t)640 * 8 * 2;            // 10 KB
    float*    part  = (float*)ws;                  // 2*64*200*16 f32 = 1.64 MB (total ~19.3 MB)

    prep_kernel<<<dim3(7, 2, BBATCH), 256, 0, stream>>>(sent1, sent2, kernel,
                                                        n1inv, n2inv, h1, h2, ksqt);

    const int lds_bytes = (112 * PS + 112 * PP + 5120) * 2;   // 87,296 B
    hipFuncSetAttribute((const void*)maxsim_kernel,
                        hipFuncAttributeMaxDynamicSharedMemorySize, lds_bytes);
    maxsim_kernel<<<dim3(512, 1, 1), 256, lds_bytes, stream>>>(h1, h2, ksqt, n2inv, part);

    int nout = BBATCH * LL * PP;
    reduce_kernel<<<(nout + 255) / 256, 256, 0, stream>>>(part, n1inv, out);
}